// Round 9
// baseline (307.831 us; speedup 1.0000x reference)
//
#include <hip/hip_runtime.h>
#include <hip/hip_bf16.h>

// out = data @ (mask*weight)^T + bias, via bf16 MFMA.
// Round 9: faithful m201-style schedule. 256x256 tile, BK=64, dbuf-2,
// 2 K-tiles per iteration, 8 phases/iter. Per phase: {ds_read this phase's
// fragments (B persists 4 phases); stage 0/2/4 gload_lds; barrier; lgkm(0);
// MFMA one acc-quadrant x K=64; [ph3/ph7: counted vmcnt(4)]; barrier}.
// Static LDS bases (no dbuf toggle). R4's measured-zero-conflict swizzle.

#define GM 8192
#define GN 4096
#define GK 4096
#define NT (GK / 64)   // 64 K-tiles of BK=64
#define NI (NT / 2)    // 32 iterations, 2 K-tiles each

typedef __attribute__((ext_vector_type(8))) short short8;
typedef __attribute__((ext_vector_type(8))) short bf16x8;
typedef __attribute__((ext_vector_type(4))) float f32x4;

__device__ __forceinline__ short f2bf(float x) {
    unsigned u = __builtin_bit_cast(unsigned, x);
    u += 0x7fffu + ((u >> 16) & 1u);
    return (short)(u >> 16);
}

__device__ __forceinline__ void stage16(const short* g, short* l) {
    __builtin_amdgcn_global_load_lds(
        (const __attribute__((address_space(1))) unsigned int*)g,
        (__attribute__((address_space(3))) unsigned int*)l, 16, 0, 0);
}

// --- conversion: data f32 -> bf16 ---
__global__ void cvt_data_kernel(const float* __restrict__ in, short* __restrict__ out, long n) {
    long i0 = ((long)blockIdx.x * blockDim.x + threadIdx.x) * 8;
    long stride = (long)gridDim.x * blockDim.x * 8;
    for (long i = i0; i < n; i += stride) {
        float4 a = *(const float4*)(in + i);
        float4 b = *(const float4*)(in + i + 4);
        short8 o;
        o[0] = f2bf(a.x); o[1] = f2bf(a.y); o[2] = f2bf(a.z); o[3] = f2bf(a.w);
        o[4] = f2bf(b.x); o[5] = f2bf(b.y); o[6] = f2bf(b.z); o[7] = f2bf(b.w);
        *(short8*)(out + i) = o;
    }
}

// --- conversion: (mask * weight) f32 -> bf16 ---
__global__ void cvt_w_kernel(const float* __restrict__ w, const float* __restrict__ m,
                             short* __restrict__ out, long n) {
    long i0 = ((long)blockIdx.x * blockDim.x + threadIdx.x) * 8;
    long stride = (long)gridDim.x * blockDim.x * 8;
    for (long i = i0; i < n; i += stride) {
        float4 wa = *(const float4*)(w + i);
        float4 wb = *(const float4*)(w + i + 4);
        float4 ma = *(const float4*)(m + i);
        float4 mb = *(const float4*)(m + i + 4);
        short8 o;
        o[0] = f2bf(wa.x * ma.x); o[1] = f2bf(wa.y * ma.y);
        o[2] = f2bf(wa.z * ma.z); o[3] = f2bf(wa.w * ma.w);
        o[4] = f2bf(wb.x * mb.x); o[5] = f2bf(wb.y * mb.y);
        o[6] = f2bf(wb.z * mb.z); o[7] = f2bf(wb.w * mb.w);
        *(short8*)(out + i) = o;
    }
}

// LDS (shorts): dbuf d in {0,32768}: A.kb0 +0, A.kb1 +8192, B.kb0 +16384,
// B.kb1 +24576. Block [256r][32c] bf16, 64B rows, quarter-swizzle
// stored q = logical q ^ ((((row>>3)&1)<<1)|((row>>1)&1))  (measured 0-conflict).
//
// Iter i computes tiles t0=2i (d0, ph0-3) and t1=2i+1 (d1, ph4-7).
// Reads: phX quad=X%4: A frags {2q,2q+1} x kb{0,1}; B all 8 frags at ph0/ph4,
// persisted across 4 phases.
// Stages (2 lines each; line = one stage16 across 512 threads = 8 KB):
//   ph0: A(t1)->d1 (4 lines)   ph1: B.kb0(t0+2)->d0  ph2: B.kb1(t0+2)->d0
//   ph4: A(t0+2)->d0 (4)       ph5: B.kb0(t1+2)->d1  ph6: B.kb1(t1+2)->d1
// vmcnt(4) at END of ph3 confirms {B,A}(2i+1); at END of ph7 confirms
// {B,A}(2i+2) (FIFO-traced; before the trailing barrier -> cross-wave safe).
// Tail: last iter ph3 uses vmcnt(0); stages guarded by st=(i+1<NI).
__global__ __launch_bounds__(512, 2) void gemm_8w(const short* __restrict__ A,
                                                  const short* __restrict__ B,
                                                  const float* __restrict__ bias,
                                                  float* __restrict__ C) {
    __shared__ short lds[65536];  // 128 KB

    const int tid  = threadIdx.x;
    const int lane = tid & 63;
    const int wid  = tid >> 6;   // 0..7
    const int wr   = wid >> 2;   // 0..1  (wave row: 128 rows)
    const int wc   = wid & 3;    // 0..3  (wave col: 64 cols)

    // XCD-aware bijective swizzle: nwg = 512, % 8 == 0
    const int bid  = blockIdx.x;
    const int swz  = (bid & 7) * 64 + (bid >> 3);
    const int brow = (swz >> 4) << 8;   // 32 M-tiles
    const int bcol = (swz & 15) << 8;   // 16 N-tiles

    // ---- staging constants (pre-swizzled global source; linear LDS dest) ----
    const int trow = tid >> 2;          // row within 128-row line
    const int qlog = (tid & 3) ^ ((((trow >> 3) & 1) << 1) | ((trow >> 1) & 1));

    // ---- fragment-read constants (swizzled LDS read) ----
    const int l15 = lane & 15;
    const int q   = lane >> 4;
    const int qx  = (((l15 >> 3) & 1) << 1) | ((l15 >> 1) & 1);
    const int foff = l15 * 32 + ((q ^ qx) << 3);   // shorts, within block
    const int aW = wr * 4096;                       // + dbuf + kb*8192 + m*512
    const int bW = wc * 2048;                       // + dbuf + 16384 + kb*8192 + n*512

    f32x4 acc[8][4] = {};
    bf16x8 af[4], bfr[8];   // af: this phase's A quad (mm*2+kb); bfr: n*2+kb, persists

    auto stA = [&](int kb, int dbase, size_t kcol) {
        #pragma unroll
        for (int j = 0; j < 2; ++j)
            stage16(A + (size_t)(brow + j * 128 + trow) * GK + kcol + kb * 32 + qlog * 8,
                    &lds[dbase + kb * 8192 + j * 4096 + wid * 512]);
    };
    auto stB = [&](int kb, int dbase, size_t kcol) {
        #pragma unroll
        for (int j = 0; j < 2; ++j)
            stage16(B + (size_t)(bcol + j * 128 + trow) * GK + kcol + kb * 32 + qlog * 8,
                    &lds[dbase + 16384 + kb * 8192 + j * 4096 + wid * 512]);
    };

    // ---- prologue: A(0),B(0)->d0, B(1)->d1 (12 loads); confirm A(0),B(0) ----
    stA(0, 0, 0); stA(1, 0, 0);
    stB(0, 0, 0); stB(1, 0, 0);
    stB(0, 32768, 64); stB(1, 32768, 64);
    asm volatile("s_waitcnt vmcnt(4)" ::: "memory");   // leaves B(1) in flight
    __builtin_amdgcn_s_barrier();
    asm volatile("" ::: "memory");

#define PH(DB, QD, LOADB, STG, LGKM8, VM)                                          \
  {                                                                                 \
    _Pragma("unroll")                                                               \
    for (int mm = 0; mm < 2; ++mm)                                                  \
      _Pragma("unroll")                                                             \
      for (int kb = 0; kb < 2; ++kb)                                                \
        af[mm * 2 + kb] =                                                           \
            *(const bf16x8*)&lds[(DB) + kb * 8192 + aW + ((QD) * 2 + mm) * 512 + foff]; \
    if (LOADB) {                                                                    \
      _Pragma("unroll")                                                             \
      for (int n = 0; n < 4; ++n)                                                   \
        _Pragma("unroll")                                                           \
        for (int kb = 0; kb < 2; ++kb)                                              \
          bfr[n * 2 + kb] =                                                         \
              *(const bf16x8*)&lds[(DB) + 16384 + kb * 8192 + bW + n * 512 + foff]; \
    }                                                                               \
    STG;                                                                            \
    if (LGKM8) { asm volatile("s_waitcnt lgkmcnt(8)" ::: "memory"); }               \
    __builtin_amdgcn_s_barrier();                                                   \
    asm volatile("s_waitcnt lgkmcnt(0)" ::: "memory");                              \
    __builtin_amdgcn_sched_barrier(0);                                              \
    __builtin_amdgcn_s_setprio(1);                                                  \
    _Pragma("unroll")                                                               \
    for (int mm = 0; mm < 2; ++mm)                                                  \
      _Pragma("unroll")                                                             \
      for (int n = 0; n < 4; ++n)                                                   \
        _Pragma("unroll")                                                           \
        for (int kb = 0; kb < 2; ++kb)                                              \
          acc[(QD) * 2 + mm][n] = __builtin_amdgcn_mfma_f32_16x16x32_bf16(          \
              af[mm * 2 + kb], bfr[n * 2 + kb], acc[(QD) * 2 + mm][n], 0, 0, 0);    \
    __builtin_amdgcn_s_setprio(0);                                                  \
    VM;                                                                             \
    __builtin_amdgcn_s_barrier();                                                   \
    asm volatile("" ::: "memory");                                                  \
  }

    for (int i = 0; i < NI; ++i) {
        const bool st = (i + 1 < NI);
        const size_t k1 = (size_t)(2 * i + 1) * 64;
        const size_t k2 = (size_t)(2 * i + 2) * 64;
        const size_t k3 = (size_t)(2 * i + 3) * 64;

        PH(0, 0, true,  { stA(0, 32768, k1); stA(1, 32768, k1); }, true, )
        PH(0, 1, false, { if (st) stB(0, 0, k2); }, false, )
        PH(0, 2, false, { if (st) stB(1, 0, k2); }, false, )
        PH(0, 3, false, { }, false,
           if (st) { asm volatile("s_waitcnt vmcnt(4)" ::: "memory"); }
           else    { asm volatile("s_waitcnt vmcnt(0)" ::: "memory"); })
        PH(32768, 0, true,  { if (st) { stA(0, 0, k2); stA(1, 0, k2); } }, true, )
        PH(32768, 1, false, { if (st) stB(0, 32768, k3); }, false, )
        PH(32768, 2, false, { if (st) stB(1, 32768, k3); }, false, )
        PH(32768, 3, false, { }, false,
           if (st) { asm volatile("s_waitcnt vmcnt(4)" ::: "memory"); })
    }
#undef PH

    // ---- epilogue: C/D layout col = lane&15, row = (lane>>4)*4 + r ----
    #pragma unroll
    for (int n = 0; n < 4; ++n) {
        const int col = bcol + wc * 64 + n * 16 + l15;
        const float bv = bias[col];
        #pragma unroll
        for (int m = 0; m < 8; ++m) {
            const int rowb = brow + wr * 128 + m * 16 + (q << 2);
            #pragma unroll
            for (int r = 0; r < 4; ++r)
                C[(size_t)(rowb + r) * GN + col] = acc[m][n][r] + bv;
        }
    }
}

extern "C" void kernel_launch(void* const* d_in, const int* in_sizes, int n_in,
                              void* d_out, int out_size, void* d_ws, size_t ws_size,
                              hipStream_t stream) {
    const float* data   = (const float*)d_in[0];  // [8192,4096]
    const float* weight = (const float*)d_in[1];  // [4096,4096]
    const float* mask   = (const float*)d_in[2];  // [4096,4096]
    const float* bias   = (const float*)d_in[3];  // [4096]
    float* out = (float*)d_out;

    short* dataB = (short*)d_ws;                  // 64 MB bf16 data
    short* wB    = dataB + (size_t)GM * GK;       // 32 MB bf16 masked weight

    cvt_data_kernel<<<2048, 256, 0, stream>>>(data, dataB, (long)GM * GK);
    cvt_w_kernel<<<2048, 256, 0, stream>>>(weight, mask, wB, (long)GN * GK);

    // grid = (8192/256) * (4096/256) = 32 * 16 = 512 workgroups, 8 waves each
    gemm_8w<<<512, 512, 0, stream>>>(dataB, wB, bias, out);
}